// Round 1
// baseline (625.979 us; speedup 1.0000x reference)
//
#include <hip/hip_runtime.h>

#define N_NODES 100000
#define N_EDGES 3200000

// ---------------- kernels ----------------

// Count in-degree (dst side). deg starts zeroed; self-loop (+1) added later.
__global__ void k_deg(const int* __restrict__ dst, int* __restrict__ deg, int E) {
    int i = blockIdx.x * blockDim.x + threadIdx.x;
    if (i < E) atomicAdd(&deg[dst[i]], 1);
}

// Per-node: dinv = rsqrt(deg+1);  s = dinv * x
__global__ void k_node1(const float* __restrict__ x, const int* __restrict__ deg,
                        float* __restrict__ dinv, float* __restrict__ s, int n) {
    int v = blockIdx.x * blockDim.x + threadIdx.x;
    if (v < n) {
        float di = rsqrtf((float)(deg[v] + 1));
        dinv[v] = di;
        s[v]    = di * x[v];
    }
}

// Scalar scatter: agg1[dst] += s[src]
__global__ void k_scatter1(const int* __restrict__ src, const int* __restrict__ dst,
                           const float* __restrict__ s, float* __restrict__ agg1, int E) {
    int i = blockIdx.x * blockDim.x + threadIdx.x;
    if (i < E) atomicAdd(&agg1[dst[i]], s[src[i]]);
}

// Per-node: a = dinv*(agg1+s);  h[f]=relu(a*W1[f]+b1[f]);  z[c]=dinv*sum_f h[f]*W2[f][c]
__global__ void k_node2(const float* __restrict__ dinv, const float* __restrict__ s,
                        const float* __restrict__ agg1,
                        const float* __restrict__ W1, const float* __restrict__ b1,
                        const float* __restrict__ W2,
                        float2* __restrict__ z, int n) {
    int v = blockIdx.x * blockDim.x + threadIdx.x;
    if (v < n) {
        float di = dinv[v];
        float a  = di * (agg1[v] + s[v]);
        float z0 = 0.f, z1 = 0.f;
#pragma unroll
        for (int f = 0; f < 16; ++f) {
            float h = fmaxf(a * W1[f] + b1[f], 0.f);
            z0 += h * W2[2 * f + 0];
            z1 += h * W2[2 * f + 1];
        }
        z[v] = make_float2(di * z0, di * z1);
    }
}

// float2 scatter: agg2[dst] += z[src]
__global__ void k_scatter2(const int* __restrict__ src, const int* __restrict__ dst,
                           const float2* __restrict__ z, float* __restrict__ agg2, int E) {
    int i = blockIdx.x * blockDim.x + threadIdx.x;
    if (i < E) {
        float2 zz = z[src[i]];
        int d = dst[i];
        atomicAdd(&agg2[2 * d + 0], zz.x);
        atomicAdd(&agg2[2 * d + 1], zz.y);
    }
}

// Epilogue: out[v][c] = dinv[v]*(agg2[v][c] + z[v][c]) + b2[c]
__global__ void k_out(const float* __restrict__ dinv, const float2* __restrict__ z,
                      const float2* __restrict__ agg2, const float* __restrict__ b2,
                      float2* __restrict__ out, int n) {
    int v = blockIdx.x * blockDim.x + threadIdx.x;
    if (v < n) {
        float di = dinv[v];
        float2 a = agg2[v];
        float2 zz = z[v];
        float2 o;
        o.x = di * (a.x + zz.x) + b2[0];
        o.y = di * (a.y + zz.y) + b2[1];
        out[v] = o;
    }
}

// ---------------- launch ----------------

extern "C" void kernel_launch(void* const* d_in, const int* in_sizes, int n_in,
                              void* d_out, int out_size, void* d_ws, size_t ws_size,
                              hipStream_t stream) {
    const float* x    = (const float*)d_in[0];
    const int*   eidx = (const int*)d_in[1];   // int64 in ref -> int32 on device per harness
    const float* W1   = (const float*)d_in[2];
    const float* b1   = (const float*)d_in[3];
    const float* W2   = (const float*)d_in[4];
    const float* b2   = (const float*)d_in[5];
    float* out = (float*)d_out;

    const int n = N_NODES;
    const int E = N_EDGES;
    const int* src = eidx;
    const int* dst = eidx + E;

    // workspace layout (floats):
    // [0,n)    deg (int)       -- zeroed
    // [n,2n)   agg1            -- zeroed
    // [2n,4n)  agg2            -- zeroed
    // [4n,5n)  dinv
    // [5n,6n)  s
    // [6n,8n)  z
    float* ws   = (float*)d_ws;
    int*   deg  = (int*)ws;
    float* agg1 = ws + n;
    float* agg2 = ws + 2 * n;
    float* dinv = ws + 4 * n;
    float* s    = ws + 5 * n;
    float* z    = ws + 6 * n;

    // zero deg+agg1+agg2 in one contiguous memset (4n floats)
    hipMemsetAsync(d_ws, 0, (size_t)4 * n * sizeof(float), stream);

    const int B = 256;
    const int gridE = (E + B - 1) / B;
    const int gridN = (n + B - 1) / B;

    k_deg<<<gridE, B, 0, stream>>>(dst, deg, E);
    k_node1<<<gridN, B, 0, stream>>>(x, deg, dinv, s, n);
    k_scatter1<<<gridE, B, 0, stream>>>(src, dst, s, agg1, E);
    k_node2<<<gridN, B, 0, stream>>>(dinv, s, agg1, W1, b1, W2, (float2*)z, n);
    k_scatter2<<<gridE, B, 0, stream>>>(src, dst, (const float2*)z, agg2, E);
    k_out<<<gridN, B, 0, stream>>>(dinv, (const float2*)z, (const float2*)agg2, b2,
                                   (float2*)out, n);
}

// Round 2
// 611.862 us; speedup vs baseline: 1.0231x; 1.0231x over previous
//
#include <hip/hip_runtime.h>

#define N_NODES 100000
#define N_EDGES 3200000
#define NXCD 8

// Physical XCD id (0..7 on MI355X), uniform per workgroup (all waves of a WG
// are on one CU -> one XCD). Correctness does NOT depend on dispatch order.
__device__ __forceinline__ unsigned get_xcc_id() {
    unsigned x;
    asm volatile("s_getreg_b32 %0, hwreg(HW_REG_XCC_ID)" : "=s"(x));
    return x & 7u;
}

template <bool PRIV>
__device__ __forceinline__ void atom_add_f(float* p, float v) {
    if constexpr (PRIV)
        __hip_atomic_fetch_add(p, v, __ATOMIC_RELAXED, __HIP_MEMORY_SCOPE_WORKGROUP);
    else
        atomicAdd(p, v);
}

template <bool PRIV>
__device__ __forceinline__ void atom_add_i(int* p, int v) {
    if constexpr (PRIV)
        __hip_atomic_fetch_add(p, v, __ATOMIC_RELAXED, __HIP_MEMORY_SCOPE_WORKGROUP);
    else
        atomicAdd(p, v);
}

// ---------------- edge kernels (4 edges / thread, int4 loads) ----------------

template <bool PRIV>
__global__ void k_deg(const int* __restrict__ dst, int* __restrict__ deg) {
    int t = blockIdx.x * blockDim.x + threadIdx.x;
    int base = t * 4;
    if (base >= N_EDGES) return;
    int* my = deg + (PRIV ? get_xcc_id() * N_NODES : 0u);
    int4 d = *(const int4*)(dst + base);
    atom_add_i<PRIV>(&my[d.x], 1);
    atom_add_i<PRIV>(&my[d.y], 1);
    atom_add_i<PRIV>(&my[d.z], 1);
    atom_add_i<PRIV>(&my[d.w], 1);
}

template <bool PRIV>
__global__ void k_scatter1(const int* __restrict__ src, const int* __restrict__ dst,
                           const float* __restrict__ s, float* __restrict__ agg1) {
    int t = blockIdx.x * blockDim.x + threadIdx.x;
    int base = t * 4;
    if (base >= N_EDGES) return;
    float* my = agg1 + (PRIV ? get_xcc_id() * N_NODES : 0u);
    int4 s4 = *(const int4*)(src + base);
    int4 d4 = *(const int4*)(dst + base);
    atom_add_f<PRIV>(&my[d4.x], s[s4.x]);
    atom_add_f<PRIV>(&my[d4.y], s[s4.y]);
    atom_add_f<PRIV>(&my[d4.z], s[s4.z]);
    atom_add_f<PRIV>(&my[d4.w], s[s4.w]);
}

template <bool PRIV>
__global__ void k_scatter2(const int* __restrict__ src, const int* __restrict__ dst,
                           const float2* __restrict__ z, float* __restrict__ agg2) {
    int t = blockIdx.x * blockDim.x + threadIdx.x;
    int base = t * 4;
    if (base >= N_EDGES) return;
    float* my = agg2 + (PRIV ? get_xcc_id() * (2u * N_NODES) : 0u);
    int4 s4 = *(const int4*)(src + base);
    int4 d4 = *(const int4*)(dst + base);
    float2 z0 = z[s4.x], z1 = z[s4.y], z2 = z[s4.z], z3 = z[s4.w];
    atom_add_f<PRIV>(&my[2 * d4.x + 0], z0.x);
    atom_add_f<PRIV>(&my[2 * d4.x + 1], z0.y);
    atom_add_f<PRIV>(&my[2 * d4.y + 0], z1.x);
    atom_add_f<PRIV>(&my[2 * d4.y + 1], z1.y);
    atom_add_f<PRIV>(&my[2 * d4.z + 0], z2.x);
    atom_add_f<PRIV>(&my[2 * d4.z + 1], z2.y);
    atom_add_f<PRIV>(&my[2 * d4.w + 0], z3.x);
    atom_add_f<PRIV>(&my[2 * d4.w + 1], z3.y);
}

// ---------------- node kernels (fold the NC-copy reduction in) ----------------

template <int NC>
__global__ void k_node1(const float* __restrict__ x, const int* __restrict__ deg,
                        float* __restrict__ dinv, float* __restrict__ s) {
    int v = blockIdx.x * blockDim.x + threadIdx.x;
    if (v >= N_NODES) return;
    int d = 1;  // self-loop
#pragma unroll
    for (int c = 0; c < NC; ++c) d += deg[c * N_NODES + v];
    float di = rsqrtf((float)d);
    dinv[v] = di;
    s[v] = di * x[v];
}

template <int NC>
__global__ void k_node2(const float* __restrict__ dinv, const float* __restrict__ s,
                        const float* __restrict__ agg1,
                        const float* __restrict__ W1, const float* __restrict__ b1,
                        const float* __restrict__ W2, float2* __restrict__ z) {
    int v = blockIdx.x * blockDim.x + threadIdx.x;
    if (v >= N_NODES) return;
    float acc = s[v];  // self-loop term dinv[v]*x[v]
#pragma unroll
    for (int c = 0; c < NC; ++c) acc += agg1[c * N_NODES + v];
    float di = dinv[v];
    float a = di * acc;
    float z0 = 0.f, z1 = 0.f;
#pragma unroll
    for (int f = 0; f < 16; ++f) {
        float h = fmaxf(a * W1[f] + b1[f], 0.f);
        z0 += h * W2[2 * f + 0];
        z1 += h * W2[2 * f + 1];
    }
    z[v] = make_float2(di * z0, di * z1);
}

template <int NC>
__global__ void k_out(const float* __restrict__ dinv, const float2* __restrict__ z,
                      const float2* __restrict__ agg2, const float* __restrict__ b2,
                      float2* __restrict__ out) {
    int v = blockIdx.x * blockDim.x + threadIdx.x;
    if (v >= N_NODES) return;
    float2 acc = z[v];  // self-loop term
#pragma unroll
    for (int c = 0; c < NC; ++c) {
        float2 a = agg2[c * N_NODES + v];
        acc.x += a.x;
        acc.y += a.y;
    }
    float di = dinv[v];
    out[v] = make_float2(di * acc.x + b2[0], di * acc.y + b2[1]);
}

// ---------------- launch ----------------

extern "C" void kernel_launch(void* const* d_in, const int* in_sizes, int n_in,
                              void* d_out, int out_size, void* d_ws, size_t ws_size,
                              hipStream_t stream) {
    const float* x  = (const float*)d_in[0];
    const int* eidx = (const int*)d_in[1];
    const float* W1 = (const float*)d_in[2];
    const float* b1 = (const float*)d_in[3];
    const float* W2 = (const float*)d_in[4];
    const float* b2 = (const float*)d_in[5];
    float* out = (float*)d_out;

    const int n = N_NODES;
    const int* src = eidx;
    const int* dst = eidx + N_EDGES;

    const int B = 256;
    const int gridE = (N_EDGES / 4 + B - 1) / B;  // 3125
    const int gridN = (n + B - 1) / B;            // 391

    float* ws = (float*)d_ws;
    bool priv = ws_size >= (size_t)(36 * n) * sizeof(float);

    if (priv) {
        // layout (floats): deg[8n] | agg1[8n] | agg2[16n] | dinv[n] | s[n] | z[2n]
        int*   deg  = (int*)ws;
        float* agg1 = ws + 8 * n;
        float* agg2 = ws + 16 * n;
        float* dinv = ws + 32 * n;
        float* s    = ws + 33 * n;
        float* z    = ws + 34 * n;

        hipMemsetAsync(d_ws, 0, (size_t)(32 * n) * sizeof(float), stream);

        k_deg<true><<<gridE, B, 0, stream>>>(dst, deg);
        k_node1<NXCD><<<gridN, B, 0, stream>>>(x, deg, dinv, s);
        k_scatter1<true><<<gridE, B, 0, stream>>>(src, dst, s, agg1);
        k_node2<NXCD><<<gridN, B, 0, stream>>>(dinv, s, agg1, W1, b1, W2, (float2*)z);
        k_scatter2<true><<<gridE, B, 0, stream>>>(src, dst, (const float2*)z, agg2);
        k_out<NXCD><<<gridN, B, 0, stream>>>(dinv, (const float2*)z, (const float2*)agg2,
                                             b2, (float2*)out);
    } else {
        // fallback: single copy, device-scope atomics
        int*   deg  = (int*)ws;
        float* agg1 = ws + n;
        float* agg2 = ws + 2 * n;
        float* dinv = ws + 4 * n;
        float* s    = ws + 5 * n;
        float* z    = ws + 6 * n;

        hipMemsetAsync(d_ws, 0, (size_t)(4 * n) * sizeof(float), stream);

        k_deg<false><<<gridE, B, 0, stream>>>(dst, deg);
        k_node1<1><<<gridN, B, 0, stream>>>(x, deg, dinv, s);
        k_scatter1<false><<<gridE, B, 0, stream>>>(src, dst, s, agg1);
        k_node2<1><<<gridN, B, 0, stream>>>(dinv, s, agg1, W1, b1, W2, (float2*)z);
        k_scatter2<false><<<gridE, B, 0, stream>>>(src, dst, (const float2*)z, agg2);
        k_out<1><<<gridN, B, 0, stream>>>(dinv, (const float2*)z, (const float2*)agg2,
                                          b2, (float2*)out);
    }
}

// Round 3
// 127.900 us; speedup vs baseline: 4.8943x; 4.7839x over previous
//
#include <hip/hip_runtime.h>

#define N_NODES 100000
#define N_EDGES 3200000
#define NB 782              // buckets of 128 nodes: ceil(100000/128)
#define NHB 256             // histogram / binning blocks
#define EPB (N_EDGES / NHB) // 12500 edges per binning block (exact)
#define BS 256

// ---------- phase 1: per-(bucket,block) histogram ----------
__global__ void k_hist(const int* __restrict__ dst, int* __restrict__ histM) {
    __shared__ int h[NB];
    int tid = threadIdx.x, blk = blockIdx.x;
    for (int b = tid; b < NB; b += BS) h[b] = 0;
    __syncthreads();
    int base = blk * EPB;
    for (int i = base + tid; i < base + EPB; i += BS)
        atomicAdd(&h[dst[i] >> 7], 1);
    __syncthreads();
    for (int b = tid; b < NB; b += BS) histM[b * NHB + blk] = h[b];
}

// ---------- phase 2a: exclusive scan along blocks, per bucket ----------
__global__ void k_scan(int* __restrict__ histM, int* __restrict__ btot) {
    __shared__ int sh[BS];
    int b = blockIdx.x, tid = threadIdx.x;
    int c = histM[b * NHB + tid];
    sh[tid] = c;
    __syncthreads();
    for (int off = 1; off < BS; off <<= 1) {
        int t = (tid >= off) ? sh[tid - off] : 0;
        __syncthreads();
        sh[tid] += t;
        __syncthreads();
    }
    histM[b * NHB + tid] = sh[tid] - c;  // exclusive within bucket
    if (tid == BS - 1) btot[b] = sh[tid];
}

// ---------- phase 2b: exclusive scan of bucket totals ----------
__global__ void k_base(const int* __restrict__ btot, int* __restrict__ bbase) {
    __shared__ int sh[BS];
    int tid = threadIdx.x;
    int v[4];
    int s = 0;
#pragma unroll
    for (int j = 0; j < 4; ++j) {
        int idx = tid * 4 + j;
        v[j] = (idx < NB) ? btot[idx] : 0;
        s += v[j];
    }
    sh[tid] = s;
    __syncthreads();
    for (int off = 1; off < BS; off <<= 1) {
        int t = (tid >= off) ? sh[tid - off] : 0;
        __syncthreads();
        sh[tid] += t;
        __syncthreads();
    }
    int base = sh[tid] - s;
#pragma unroll
    for (int j = 0; j < 4; ++j) {
        int idx = tid * 4 + j;
        if (idx < NB) bbase[idx] = base;
        base += v[j];
    }
}

// ---------- phase 3: scatter edges into bucket segments ----------
// packed = (src << 7) | (dst & 127); src < 2^17, so fits 24 bits.
__global__ void k_bin(const int* __restrict__ src, const int* __restrict__ dst,
                      const int* __restrict__ histM, const int* __restrict__ bbase,
                      unsigned* __restrict__ binned) {
    __shared__ int off[NB];
    int tid = threadIdx.x, blk = blockIdx.x;
    for (int b = tid; b < NB; b += BS)
        off[b] = bbase[b] + histM[b * NHB + blk];
    __syncthreads();
    int base = blk * EPB;
    for (int i = base + tid; i < base + EPB; i += BS) {
        int sI = src[i], d = dst[i];
        int pos = atomicAdd(&off[d >> 7], 1);  // LDS atomic, returns rank
        binned[pos] = ((unsigned)sI << 7) | (unsigned)(d & 127);
    }
}

// ---------- phase 4: per-bucket degree + node1 (dinv, s) ----------
__global__ void k_deg_node1(const unsigned* __restrict__ binned,
                            const int* __restrict__ bbase, const int* __restrict__ btot,
                            const float* __restrict__ x,
                            float* __restrict__ dinv, float* __restrict__ s) {
    __shared__ int cnt[128];
    int tid = threadIdx.x, b = blockIdx.x;
    if (tid < 128) cnt[tid] = 0;
    __syncthreads();
    int st = bbase[b], en = st + btot[b];
    for (int i = st + tid; i < en; i += BS)
        atomicAdd(&cnt[binned[i] & 127], 1);
    __syncthreads();
    int node = b * 128 + tid;
    if (tid < 128 && node < N_NODES) {
        float di = rsqrtf((float)(cnt[tid] + 1));  // +1 self-loop
        dinv[node] = di;
        s[node] = di * x[node];
    }
}

// ---------- phase 5: per-bucket scatter1 + layer-1 MLP -> z ----------
__global__ void k_s1n2(const unsigned* __restrict__ binned,
                       const int* __restrict__ bbase, const int* __restrict__ btot,
                       const float* __restrict__ dinv, const float* __restrict__ s,
                       const float* __restrict__ W1, const float* __restrict__ b1,
                       const float* __restrict__ W2, float2* __restrict__ z) {
    __shared__ float acc[128];
    int tid = threadIdx.x, b = blockIdx.x;
    if (tid < 128) acc[tid] = 0.f;
    __syncthreads();
    int st = bbase[b], en = st + btot[b];
    for (int i = st + tid; i < en; i += BS) {
        unsigned rd = binned[i];
        atomicAdd(&acc[rd & 127], s[rd >> 7]);
    }
    __syncthreads();
    int node = b * 128 + tid;
    if (tid < 128 && node < N_NODES) {
        float di = dinv[node];
        float a = di * (acc[tid] + s[node]);  // s[node] = self-loop term
        float z0 = 0.f, z1 = 0.f;
#pragma unroll
        for (int f = 0; f < 16; ++f) {
            float h = fmaxf(a * W1[f] + b1[f], 0.f);
            z0 += h * W2[2 * f + 0];
            z1 += h * W2[2 * f + 1];
        }
        z[node] = make_float2(di * z0, di * z1);
    }
}

// ---------- phase 6: per-bucket scatter2 + epilogue -> out ----------
__global__ void k_s2out(const unsigned* __restrict__ binned,
                        const int* __restrict__ bbase, const int* __restrict__ btot,
                        const float* __restrict__ dinv, const float2* __restrict__ z,
                        const float* __restrict__ b2, float2* __restrict__ out) {
    __shared__ float accx[128], accy[128];
    int tid = threadIdx.x, b = blockIdx.x;
    if (tid < 128) { accx[tid] = 0.f; accy[tid] = 0.f; }
    __syncthreads();
    int st = bbase[b], en = st + btot[b];
    for (int i = st + tid; i < en; i += BS) {
        unsigned rd = binned[i];
        float2 zz = z[rd >> 7];
        atomicAdd(&accx[rd & 127], zz.x);
        atomicAdd(&accy[rd & 127], zz.y);
    }
    __syncthreads();
    int node = b * 128 + tid;
    if (tid < 128 && node < N_NODES) {
        float di = dinv[node];
        float2 zz = z[node];
        out[node] = make_float2(di * (accx[tid] + zz.x) + b2[0],
                                di * (accy[tid] + zz.y) + b2[1]);
    }
}

// ---------- fallback (device atomics), used only if ws too small ----------
__global__ void f_deg(const int* __restrict__ dst, int* __restrict__ deg) {
    int i = blockIdx.x * blockDim.x + threadIdx.x;
    if (i < N_EDGES) atomicAdd(&deg[dst[i]], 1);
}
__global__ void f_node1(const float* __restrict__ x, const int* __restrict__ deg,
                        float* __restrict__ dinv, float* __restrict__ s) {
    int v = blockIdx.x * blockDim.x + threadIdx.x;
    if (v < N_NODES) {
        float di = rsqrtf((float)(deg[v] + 1));
        dinv[v] = di;
        s[v] = di * x[v];
    }
}
__global__ void f_scatter1(const int* __restrict__ src, const int* __restrict__ dst,
                           const float* __restrict__ s, float* __restrict__ agg1) {
    int i = blockIdx.x * blockDim.x + threadIdx.x;
    if (i < N_EDGES) atomicAdd(&agg1[dst[i]], s[src[i]]);
}
__global__ void f_node2(const float* __restrict__ dinv, const float* __restrict__ s,
                        const float* __restrict__ agg1, const float* __restrict__ W1,
                        const float* __restrict__ b1, const float* __restrict__ W2,
                        float2* __restrict__ z) {
    int v = blockIdx.x * blockDim.x + threadIdx.x;
    if (v < N_NODES) {
        float di = dinv[v];
        float a = di * (agg1[v] + s[v]);
        float z0 = 0.f, z1 = 0.f;
#pragma unroll
        for (int f = 0; f < 16; ++f) {
            float h = fmaxf(a * W1[f] + b1[f], 0.f);
            z0 += h * W2[2 * f + 0];
            z1 += h * W2[2 * f + 1];
        }
        z[v] = make_float2(di * z0, di * z1);
    }
}
__global__ void f_scatter2(const int* __restrict__ src, const int* __restrict__ dst,
                           const float2* __restrict__ z, float* __restrict__ agg2) {
    int i = blockIdx.x * blockDim.x + threadIdx.x;
    if (i < N_EDGES) {
        float2 zz = z[src[i]];
        int d = dst[i];
        atomicAdd(&agg2[2 * d + 0], zz.x);
        atomicAdd(&agg2[2 * d + 1], zz.y);
    }
}
__global__ void f_out(const float* __restrict__ dinv, const float2* __restrict__ z,
                      const float2* __restrict__ agg2, const float* __restrict__ b2,
                      float2* __restrict__ out) {
    int v = blockIdx.x * blockDim.x + threadIdx.x;
    if (v < N_NODES) {
        float di = dinv[v];
        float2 a = agg2[v], zz = z[v];
        out[v] = make_float2(di * (a.x + zz.x) + b2[0], di * (a.y + zz.y) + b2[1]);
    }
}

// ---------- launch ----------
extern "C" void kernel_launch(void* const* d_in, const int* in_sizes, int n_in,
                              void* d_out, int out_size, void* d_ws, size_t ws_size,
                              hipStream_t stream) {
    const float* x  = (const float*)d_in[0];
    const int* eidx = (const int*)d_in[1];
    const float* W1 = (const float*)d_in[2];
    const float* b1 = (const float*)d_in[3];
    const float* W2 = (const float*)d_in[4];
    const float* b2 = (const float*)d_in[5];
    float* out = (float*)d_out;

    const int n = N_NODES;
    const int* src = eidx;
    const int* dst = eidx + N_EDGES;

    // workspace layout (ints/floats, 16B-aligned regions):
    // histM[NB*NHB] | btot[1024] | bbase[1024] | binned[E] | dinv[n] | s[n] | z[2n]
    size_t oHist = 0;
    size_t oBtot = oHist + (size_t)NB * NHB;          // 200192
    size_t oBbase = oBtot + 1024;
    size_t oBin  = oBbase + 1024;
    size_t oDinv = oBin + N_EDGES;
    size_t oS    = oDinv + n;
    size_t oZ    = oS + n;
    size_t need  = (oZ + 2 * n) * sizeof(int);

    if (ws_size >= need) {
        int* wsI = (int*)d_ws;
        int* histM = wsI + oHist;
        int* btot  = wsI + oBtot;
        int* bbase = wsI + oBbase;
        unsigned* binned = (unsigned*)(wsI + oBin);
        float* dinv = (float*)(wsI + oDinv);
        float* s    = (float*)(wsI + oS);
        float* z    = (float*)(wsI + oZ);

        k_hist<<<NHB, BS, 0, stream>>>(dst, histM);
        k_scan<<<NB, BS, 0, stream>>>(histM, btot);
        k_base<<<1, BS, 0, stream>>>(btot, bbase);
        k_bin<<<NHB, BS, 0, stream>>>(src, dst, histM, bbase, binned);
        k_deg_node1<<<NB, BS, 0, stream>>>(binned, bbase, btot, x, dinv, s);
        k_s1n2<<<NB, BS, 0, stream>>>(binned, bbase, btot, dinv, s, W1, b1, W2,
                                      (float2*)z);
        k_s2out<<<NB, BS, 0, stream>>>(binned, bbase, btot, dinv, (const float2*)z,
                                       b2, (float2*)out);
    } else {
        // fallback: device-scope atomics (round-1 structure)
        float* ws = (float*)d_ws;
        int* deg    = (int*)ws;
        float* agg1 = ws + n;
        float* agg2 = ws + 2 * n;
        float* dinv = ws + 4 * n;
        float* s    = ws + 5 * n;
        float* z    = ws + 6 * n;
        hipMemsetAsync(d_ws, 0, (size_t)(4 * n) * sizeof(float), stream);
        const int gridE = (N_EDGES + BS - 1) / BS;
        const int gridN = (n + BS - 1) / BS;
        f_deg<<<gridE, BS, 0, stream>>>(dst, deg);
        f_node1<<<gridN, BS, 0, stream>>>(x, deg, dinv, s);
        f_scatter1<<<gridE, BS, 0, stream>>>(src, dst, s, agg1);
        f_node2<<<gridN, BS, 0, stream>>>(dinv, s, agg1, W1, b1, W2, (float2*)z);
        f_scatter2<<<gridE, BS, 0, stream>>>(src, dst, (const float2*)z, agg2);
        f_out<<<gridN, BS, 0, stream>>>(dinv, (const float2*)z, (const float2*)agg2,
                                        b2, (float2*)out);
    }
}